// Round 7
// baseline (259.207 us; speedup 1.0000x reference)
//
#include <hip/hip_runtime.h>
#include <hip/hip_bf16.h>
#include <math.h>

// Problem dims
constexpr int BD = 32;
constexpr int SD = 512;
constexpr int RD = 49;
constexpr int HD = 768;
constexpr int MT = BD * SD;    // 16384 text rows
constexpr int MI = BD * RD;    // 1568 img rows
constexpr int NP = 6;          // 3 n-blocks x 2 wave-columns partials per row
// 256x256 gemm geometry
constexpr int MBT3 = MT / 256; // 64 text m-blocks
constexpr int MBI3 = 7;        // img m-blocks (1792 padded rows; OOB reads land in wt_t, in-bounds)
constexpr int NB3 = 3;         // 768/256 n-blocks
constexpr int NWG3 = (MBT3 + MBI3) * NB3;  // 213 blocks
constexpr int NT3 = HD / 64;   // 12 K-steps (BK=64)

typedef __bf16 bf16;
typedef __bf16 bf16x4 __attribute__((ext_vector_type(4)));
typedef __bf16 bf16x8 __attribute__((ext_vector_type(8)));
typedef float f32x4 __attribute__((ext_vector_type(4)));

#define GLOAD_LDS16(g, l) __builtin_amdgcn_global_load_lds( \
    (__attribute__((address_space(1))) void*)(g),           \
    (__attribute__((address_space(3))) void*)(l), 16, 0, 0)
#define BAR() __builtin_amdgcn_s_barrier()
#define SCHED_FENCE() __builtin_amdgcn_sched_barrier(0)
#define WAITV(n) asm volatile("s_waitcnt vmcnt(" #n ")" ::: "memory")

__device__ __forceinline__ float fast_tanh(float x) {
    const float e = __expf(2.f * x);
    return 1.f - 2.f / (e + 1.f);
}

// ---------------------------------------------------------------------------
// prep_text: text fp32 -> text_bf (bf16) AND s_txt[row] = text[row,:].v_f
// ---------------------------------------------------------------------------
__global__ __launch_bounds__(256) void prep_text(
    const float* __restrict__ text, const float* __restrict__ v_f,
    bf16* __restrict__ text_bf, float* __restrict__ s_txt)
{
    const int row = blockIdx.x * 4 + (threadIdx.x >> 6);
    const int lane = threadIdx.x & 63;
    const float* tr = text + (size_t)row * HD;
    bf16* tb = text_bf + (size_t)row * HD;
    float acc = 0.f;
    #pragma unroll
    for (int c = 0; c < 3; ++c) {
        const int o = c * 256 + lane * 4;
        const f32x4 x = *(const f32x4*)(tr + o);
        const f32x4 v = *(const f32x4*)(v_f + o);
        bf16x4 b; b[0] = (bf16)x[0]; b[1] = (bf16)x[1]; b[2] = (bf16)x[2]; b[3] = (bf16)x[3];
        *(bf16x4*)(tb + o) = b;
        acc += x[0] * v[0] + x[1] * v[1] + x[2] * v[2] + x[3] * v[3];
    }
    for (int off = 32; off; off >>= 1) acc += __shfl_xor(acc, off);
    if (lane == 0) s_txt[row] = acc;
}

// ---------------------------------------------------------------------------
// prep_misc: fused vf_vm (385 blk) + conv_img (588 blk) + transpose_w (288 blk)
// ---------------------------------------------------------------------------
__global__ __launch_bounds__(256) void prep_misc(
    const float* __restrict__ ft_w, const float* __restrict__ fm_w,
    const float* __restrict__ fm_b, const float* __restrict__ fg_w,
    float* __restrict__ v_f, float* __restrict__ v_m, float* __restrict__ c_m,
    const float* __restrict__ img, bf16* __restrict__ img_bf,
    const float* __restrict__ t2_w, const float* __restrict__ i1_w,
    bf16* __restrict__ wt_t, bf16* __restrict__ wt_i)
{
    __shared__ float tile[64][65];
    const int bid = blockIdx.x;
    if (bid < 385) {
        const int idx = bid * 4 + (threadIdx.x >> 6);
        const int lane = threadIdx.x & 63;
        const float* row; const float* vecp; float* outp;
        if (idx < HD)            { row = ft_w + (size_t)idx * HD;        vecp = fg_w;      outp = v_f + idx; }
        else if (idx < 2 * HD)   { row = fm_w + (size_t)(idx - HD) * HD; vecp = fg_w + HD; outp = v_m + (idx - HD); }
        else if (idx == 2 * HD)  { row = fm_b;                           vecp = fg_w + HD; outp = c_m; }
        else return;
        float acc = 0.f;
        #pragma unroll
        for (int i = 0; i < HD / 64; ++i) acc += row[lane + 64 * i] * vecp[lane + 64 * i];
        for (int off = 32; off; off >>= 1) acc += __shfl_xor(acc, off);
        if (lane == 0) *outp = acc;
    } else if (bid < 385 + 588) {
        const int i = (bid - 385) * 256 + threadIdx.x;
        const int n8 = BD * RD * HD / 8;
        if (i >= n8) return;
        const size_t o = (size_t)i * 8;
        const f32x4 x0 = *(const f32x4*)(img + o);
        const f32x4 x1 = *(const f32x4*)(img + o + 4);
        bf16x8 b;
        b[0]=(bf16)x0[0]; b[1]=(bf16)x0[1]; b[2]=(bf16)x0[2]; b[3]=(bf16)x0[3];
        b[4]=(bf16)x1[0]; b[5]=(bf16)x1[1]; b[6]=(bf16)x1[2]; b[7]=(bf16)x1[3];
        *(bf16x8*)(img_bf + o) = b;
    } else {
        const int idx2 = bid - (385 + 588);
        const int z = idx2 / 144, rem = idx2 % 144;
        const int bx = rem % 12, by = rem / 12;
        const float* W = z ? i1_w : t2_w;
        bf16* Wt = z ? wt_i : wt_t;
        const int k0 = bx * 64, n0 = by * 64;
        const int t = threadIdx.x;
        const int rb = t >> 6, c = t & 63;
        #pragma unroll
        for (int i = 0; i < 16; ++i) {
            const int r = rb + i * 4;
            tile[r][c] = W[(size_t)(k0 + r) * HD + n0 + c];
        }
        __syncthreads();
        #pragma unroll
        for (int i = 0; i < 16; ++i) {
            const int r = rb + i * 4;
            Wt[(size_t)(n0 + r) * HD + k0 + c] = (bf16)tile[c][r];
        }
    }
}

// ---------------------------------------------------------------------------
// gemm4: gemm3 + 4-phase compute schedule (T3) + setprio around MFMA (T5).
// 256x256 tile, BK=64, 8 waves, double-buffered LDS (128KB), issue-early
// stage + counted vmcnt(8), conflict-free chunked LDS, XCD swizzle.
// Per K-tile: 4 phases of {quadrant ds_read; setprio(1); 16 MFMA; setprio(0);
// s_barrier} -> wave role diversity so ds_read of one wave overlaps MFMA of
// another (m218b/m196 mechanism). Barrier count uniform across waves.
// ---------------------------------------------------------------------------
__global__ __launch_bounds__(512, 2) void gemm4(
    const bf16* __restrict__ Atext, const bf16* __restrict__ WtT,
    const float* __restrict__ vecT, float* __restrict__ partT,
    const bf16* __restrict__ Aimg, const bf16* __restrict__ WtI,
    const float* __restrict__ vecI, float* __restrict__ partI)
{
    __shared__ __align__(16) bf16 As[2 * 16384];
    __shared__ __align__(16) bf16 Bs[2 * 16384];

    const int bid = blockIdx.x;
    const int q = NWG3 / 8, r = NWG3 % 8;
    const int xcd = bid % 8, sidx = bid / 8;
    const int o = (xcd < r ? xcd * (q + 1) : r * (q + 1) + (xcd - r) * q) + sidx;
    const int mb = o / NB3, nb = o % NB3;

    const bool isT = mb < MBT3;
    const bf16* A    = isT ? Atext : Aimg;
    const bf16* Wt   = isT ? WtT : WtI;
    const float* vec = isT ? vecT : vecI;
    float* part      = isT ? partT : partI;
    const int m0 = (isT ? mb : mb - MBT3) * 256;
    const int n0 = nb * 256;

    const int t = threadIdx.x;
    const int w = t >> 6, lane = t & 63;
    const int quad = lane >> 4, l16 = lane & 15;
    const int wm_idx = w & 3, wn_idx = w >> 2;
    const int wm2 = wm_idx * 64, wn2 = wn_idx * 128;

    const bf16* Ag = A  + (size_t)(m0 + l16) * HD + quad * 8;
    const bf16* Bg = Wt + (size_t)(n0 + l16) * HD + quad * 8;

    f32x4 acc[4][8] = {};

#define STAGE4(tt, bb) {                                                     \
    const int kk = (tt) * 64;                                                \
    _Pragma("unroll")                                                        \
    for (int h = 0; h < 2; ++h) {                                            \
        _Pragma("unroll")                                                    \
        for (int j = 0; j < 2; ++j) {                                        \
            const int rc = 2 * w + j;                                        \
            GLOAD_LDS16(Ag + (size_t)rc * 16 * HD + kk + h * 32,             \
                        As + (bb) * 16384 + (h * 16 + rc) * 512);            \
            GLOAD_LDS16(Bg + (size_t)rc * 16 * HD + kk + h * 32,             \
                        Bs + (bb) * 16384 + (h * 16 + rc) * 512);            \
        }                                                                    \
    }                                                                        \
}

    // phased compute of buffer bb: 4 phases x {ds_read quadrant, prio-MFMA, bar}
#define COMPUTE4(bb) {                                                       \
    const bf16* Asl = As + (bb) * 16384;                                     \
    const bf16* Bsl = Bs + (bb) * 16384;                                     \
    bf16x8 af[4], bg[4];                                                     \
    _Pragma("unroll")                                                        \
    for (int h = 0; h < 2; ++h) {                                            \
        /* phase h.1: af[0..3] + bg fj=0..3 */                               \
        _Pragma("unroll")                                                    \
        for (int fi = 0; fi < 4; ++fi)                                       \
            af[fi] = *(const bf16x8*)(Asl + (h * 16 + wm_idx * 4 + fi) * 512 + lane * 8); \
        _Pragma("unroll")                                                    \
        for (int fj = 0; fj < 4; ++fj)                                       \
            bg[fj] = *(const bf16x8*)(Bsl + (h * 16 + wn_idx * 8 + fj) * 512 + lane * 8); \
        __builtin_amdgcn_s_setprio(1);                                       \
        _Pragma("unroll")                                                    \
        for (int fi = 0; fi < 4; ++fi)                                       \
            _Pragma("unroll")                                                \
            for (int fj = 0; fj < 4; ++fj)                                   \
                acc[fi][fj] = __builtin_amdgcn_mfma_f32_16x16x32_bf16(       \
                    af[fi], bg[fj], acc[fi][fj], 0, 0, 0);                   \
        __builtin_amdgcn_s_setprio(0);                                       \
        BAR();                                                               \
        /* phase h.2: bg fj=4..7 (af reused) */                              \
        _Pragma("unroll")                                                    \
        for (int fj = 0; fj < 4; ++fj)                                       \
            bg[fj] = *(const bf16x8*)(Bsl + (h * 16 + wn_idx * 8 + 4 + fj) * 512 + lane * 8); \
        __builtin_amdgcn_s_setprio(1);                                       \
        _Pragma("unroll")                                                    \
        for (int fi = 0; fi < 4; ++fi)                                       \
            _Pragma("unroll")                                                \
            for (int fj = 0; fj < 4; ++fj)                                   \
                acc[fi][4 + fj] = __builtin_amdgcn_mfma_f32_16x16x32_bf16(   \
                    af[fi], bg[fj], acc[fi][4 + fj], 0, 0, 0);               \
        __builtin_amdgcn_s_setprio(0);                                       \
        BAR();                                                               \
    }                                                                        \
}

    STAGE4(0, 0);
    for (int tt = 0; tt < NT3; ++tt) {
        if (tt + 1 < NT3) {
            STAGE4(tt + 1, (tt + 1) & 1);
            WAITV(8);      // tile tt's 8 loads arrived; tt+1's 8 in flight
        } else {
            WAITV(0);
        }
        BAR();             // buffer tt&1 visible to all waves
        SCHED_FENCE();
        COMPUTE4(tt & 1);  // 4 phases; final phase BAR doubles as the
        SCHED_FENCE();     // read-done fence before next iter restages tt&1
    }

#undef STAGE4
#undef COMPUTE4

    float vv[8];
    #pragma unroll
    for (int fj = 0; fj < 8; ++fj) vv[fj] = vec[n0 + wn2 + fj * 16 + l16];

    #pragma unroll
    for (int fi = 0; fi < 4; ++fi) {
        #pragma unroll
        for (int reg = 0; reg < 4; ++reg) {
            float p = 0.f;
            #pragma unroll
            for (int fj = 0; fj < 8; ++fj)
                p += fast_tanh(acc[fi][fj][reg]) * vv[fj];
            p += __shfl_xor(p, 1);
            p += __shfl_xor(p, 2);
            p += __shfl_xor(p, 4);
            p += __shfl_xor(p, 8);
            if (l16 == 0) {
                const int row = m0 + wm2 + fi * 16 + quad * 4 + reg;
                part[(size_t)row * NP + nb * 2 + wn_idx] = p;
            }
        }
    }
}

// ---------------------------------------------------------------------------
// wsum3: fused partial-reduce + softmax + weighted sum, VECTORIZED. (R6 frozen)
// ---------------------------------------------------------------------------
__global__ __launch_bounds__(256) void wsum3(
    const float* __restrict__ k_part, const float* __restrict__ i_part,
    const bf16* __restrict__ text_bf, const float* __restrict__ img,
    float* __restrict__ at_part, float* __restrict__ aimg)
{
    __shared__ float S[SD];
    __shared__ float red[4];
    __shared__ float P2[2][96][8];
    const int bid = blockIdx.x;
    const int t = threadIdx.x;

    if (bid < 128) {
        const int b = bid >> 2, jq = bid & 3;
        for (int j = t; j < SD; j += 256) {
            const float* p = k_part + (size_t)(b * SD + j) * NP;
            S[j] = p[0] + p[1] + p[2] + p[3] + p[4] + p[5];
        }
        __syncthreads();
        float m = fmaxf(S[t], S[t + 256]);
        for (int off = 32; off; off >>= 1) m = fmaxf(m, __shfl_xor(m, off));
        if ((t & 63) == 0) red[t >> 6] = m;
        __syncthreads();
        m = fmaxf(fmaxf(red[0], red[1]), fmaxf(red[2], red[3]));
        const float e0 = __expf(S[t] - m), e1 = __expf(S[t + 256] - m);
        S[t] = e0; S[t + 256] = e1;
        float lsum = e0 + e1;
        for (int off = 32; off; off >>= 1) lsum += __shfl_xor(lsum, off);
        __syncthreads();
        if ((t & 63) == 0) red[t >> 6] = lsum;
        __syncthreads();
        const float inv = 1.f / (red[0] + red[1] + red[2] + red[3]);
        const int o = t % 96, jh = t / 96;
        if (jh < 2) {
            float a[8] = {};
            const bf16* Xb = text_bf + ((size_t)b * SD + jq * 128 + jh * 64) * HD + o * 8;
            const float* Sp = S + jq * 128 + jh * 64;
            #pragma unroll 8
            for (int jj = 0; jj < 64; ++jj) {
                const bf16x8 v = *(const bf16x8*)(Xb + (size_t)jj * HD);
                const float s = Sp[jj];
                #pragma unroll
                for (int e = 0; e < 8; ++e) a[e] += s * (float)v[e];
            }
            #pragma unroll
            for (int e = 0; e < 8; ++e) P2[jh][o][e] = a[e];
        }
        __syncthreads();
        if (t < 96) {
            float* dst = at_part + ((size_t)(b * 4 + jq)) * HD + t * 8;
            f32x4 o0, o1;
            #pragma unroll
            for (int e = 0; e < 4; ++e) o0[e] = (P2[0][t][e] + P2[1][t][e]) * inv;
            #pragma unroll
            for (int e = 0; e < 4; ++e) o1[e] = (P2[0][t][e + 4] + P2[1][t][e + 4]) * inv;
            *(f32x4*)dst = o0;
            *(f32x4*)(dst + 4) = o1;
        }
    } else {
        const int idx = bid - 128;
        const int b = idx & 31, hy = idx >> 5;
        if (t < 64) {
            float s0 = -1e30f;
            if (t < RD) {
                const float* p = i_part + (size_t)(b * RD + t) * NP;
                s0 = p[0] + p[1] + p[2] + p[3] + p[4] + p[5];
            }
            float m = s0;
            for (int off = 32; off; off >>= 1) m = fmaxf(m, __shfl_xor(m, off));
            float e = (t < RD) ? __expf(s0 - m) : 0.f;
            float lsum = e;
            for (int off = 32; off; off >>= 1) lsum += __shfl_xor(lsum, off);
            if (t < RD) S[t] = e;
            if (t == 0) red[0] = 1.f / lsum;
        }
        __syncthreads();
        const float inv = red[0];
        const int h = hy * 256 + t;
        const float* Xb = img + (size_t)b * RD * HD + h;
        float acc = 0.f;
        #pragma unroll 7
        for (int j = 0; j < RD; ++j) acc += S[j] * Xb[(size_t)j * HD];
        aimg[b * HD + h] = acc * inv;
    }
}

// ---------------------------------------------------------------------------
// ni_nt3: GEMV with f32x4 weight loads, 8-way K split. (R6 frozen)
// ---------------------------------------------------------------------------
__global__ __launch_bounds__(256) void ni_nt3(
    const float* __restrict__ aimg, const float* __restrict__ at_part,
    const float* __restrict__ gi_w, const float* __restrict__ gi_b,
    const float* __restrict__ gt_w, const float* __restrict__ gt_b,
    float* __restrict__ ni, float* __restrict__ nt)
{
    const int b = blockIdx.x, n0 = blockIdx.y * 128, which = blockIdx.z;
    const float* W = which ? gt_w : gi_w;
    const float* bias = which ? gt_b : gi_b;
    float* Y = which ? nt : ni;

    __shared__ float Xs[HD];
    __shared__ float part[8][32][4];
    const int t = threadIdx.x;
    if (which) {
        for (int h = t; h < HD; h += 256)
            Xs[h] = at_part[((size_t)(b * 4 + 0)) * HD + h] + at_part[((size_t)(b * 4 + 1)) * HD + h]
                  + at_part[((size_t)(b * 4 + 2)) * HD + h] + at_part[((size_t)(b * 4 + 3)) * HD + h];
    } else {
        for (int h = t; h < HD; h += 256) Xs[h] = aimg[b * HD + h];
    }
    __syncthreads();
    const int lane32 = t & 31, kq = t >> 5;
    const int n = n0 + lane32 * 4;
    f32x4 acc = {0.f, 0.f, 0.f, 0.f};
    const float* Wp = W + (size_t)(kq * 96) * HD + n;
    #pragma unroll 4
    for (int k = 0; k < 96; ++k) {
        const f32x4 wv = *(const f32x4*)(Wp + (size_t)k * HD);
        const float x = Xs[kq * 96 + k];
        acc[0] += x * wv[0]; acc[1] += x * wv[1];
        acc[2] += x * wv[2]; acc[3] += x * wv[3];
    }
    *(f32x4*)&part[kq][lane32][0] = acc;
    __syncthreads();
    if (t < 128) {
        float s = 0.f;
        #pragma unroll
        for (int q2 = 0; q2 < 8; ++q2) s += part[q2][t >> 2][t & 3];
        Y[b * HD + n0 + t] = fast_tanh(s + bias[n0 + t]);
    }
}

// ---------------------------------------------------------------------------
// gateT3: fused gate_mix + T GEMV, f32x4 weight loads. (R6 frozen)
// ---------------------------------------------------------------------------
__global__ __launch_bounds__(256) void gateT3(
    const float* __restrict__ ni, const float* __restrict__ nt,
    const float* __restrict__ gg_w, const float* __restrict__ gg_b,
    const float* __restrict__ v_m, const float* __restrict__ c_m,
    const float* __restrict__ fg_b,
    const float* __restrict__ fr_w, const float* __restrict__ fr_b,
    float* __restrict__ T, float* __restrict__ s_mm)
{
    const int b = blockIdx.x, n0 = blockIdx.y * 128, t = threadIdx.x;
    __shared__ float Mm[HD];
    __shared__ float part[8][32][4];
    __shared__ float red[4];
    __shared__ float gsh;

    float accg = 0.f;
    for (int n = t; n < HD; n += 256)
        accg += ni[b * HD + n] * gg_w[n] + nt[b * HD + n] * gg_w[HD + n];
    for (int off = 32; off; off >>= 1) accg += __shfl_xor(accg, off);
    if ((t & 63) == 0) red[t >> 6] = accg;
    __syncthreads();
    if (t == 0) gsh = 1.f / (1.f + expf(-(red[0] + red[1] + red[2] + red[3] + gg_b[0])));
    __syncthreads();
    const float g = gsh;
    float a2 = 0.f;
    for (int n = t; n < HD; n += 256) {
        const float m = g * ni[b * HD + n] + (1.f - g) * nt[b * HD + n];
        Mm[n] = m;
        a2 += m * v_m[n];
    }
    __syncthreads();
    const int lane32 = t & 31, kq = t >> 5;
    const int n = n0 + lane32 * 4;
    f32x4 acc = {0.f, 0.f, 0.f, 0.f};
    const float* Wp = fr_w + (size_t)(kq * 96) * HD + n;
    #pragma unroll 4
    for (int k = 0; k < 96; ++k) {
        const f32x4 wv = *(const f32x4*)(Wp + (size_t)k * HD);
        const float x = Mm[kq * 96 + k];
        acc[0] += x * wv[0]; acc[1] += x * wv[1];
        acc[2] += x * wv[2]; acc[3] += x * wv[3];
    }
    *(f32x4*)&part[kq][lane32][0] = acc;
    if (blockIdx.y == 0) {
        for (int off = 32; off; off >>= 1) a2 += __shfl_xor(a2, off);
        if ((t & 63) == 0) red[t >> 6] = a2;
    }
    __syncthreads();
    if (blockIdx.y == 0 && t == 0)
        s_mm[b] = red[0] + red[1] + red[2] + red[3] + *c_m + fg_b[0];
    if (t < 128) {
        float s = 0.f;
        #pragma unroll
        for (int q2 = 0; q2 < 8; ++q2) s += part[q2][t >> 2][t & 3];
        T[b * HD + n0 + t] = fast_tanh(s + fr_b[n0 + t]);
    }
}

// out[b,s,h] = sigmoid(s_txt[b,s] + s_mm[b]) * T[b,h]  (reads ws only)
__global__ __launch_bounds__(256) void out_kernel(const float* __restrict__ s_txt,
                                                  const float* __restrict__ s_mm,
                                                  const float* __restrict__ T,
                                                  float* __restrict__ out) {
    const size_t idx = ((size_t)blockIdx.x * 256 + threadIdx.x) * 4;
    const int h = (int)(idx % HD);
    const int bs = (int)(idx / HD);
    const int b = bs >> 9;
    float f = s_txt[bs] + s_mm[b];
    f = 1.f / (1.f + expf(-f));
    const float* Tp = T + b * HD + h;
    f32x4 o;
    o[0] = f * Tp[0]; o[1] = f * Tp[1]; o[2] = f * Tp[2]; o[3] = f * Tp[3];
    *(f32x4*)(out + idx) = o;
}

// ---------------------------------------------------------------------------
extern "C" void kernel_launch(void* const* d_in, const int* in_sizes, int n_in,
                              void* d_out, int out_size, void* d_ws, size_t ws_size,
                              hipStream_t stream) {
    const float* text = (const float*)d_in[0];
    const float* img  = (const float*)d_in[1];
    const float* i1_w = (const float*)d_in[4];
    const float* a1_w = (const float*)d_in[5];
    const float* t2_w = (const float*)d_in[7];
    const float* a2_w = (const float*)d_in[10];
    const float* gt_w = (const float*)d_in[12];
    const float* gt_b = (const float*)d_in[13];
    const float* gi_w = (const float*)d_in[14];
    const float* gi_b = (const float*)d_in[15];
    const float* gg_w = (const float*)d_in[16];
    const float* gg_b = (const float*)d_in[17];
    const float* ft_w = (const float*)d_in[18];
    const float* fm_w = (const float*)d_in[19];
    const float* fm_b = (const float*)d_in[20];
    const float* fg_w = (const float*)d_in[21];
    const float* fg_b = (const float*)d_in[22];
    const float* fr_w = (const float*)d_in[23];
    const float* fr_b = (const float*)d_in[24];
    float* out = (float*)d_out;

    // ---- scratch inside d_out (all uses precede out_kernel) ----
    float* sc_ = out;
    float* i_part  = sc_;                 // 1792*6 = 10752 (cap 38400)
    float* k_part  = sc_ + 38400;         // 16384*6 = 98304
    float* aimg    = sc_ + 449600;        // 24576
    float* v_f     = sc_ + 498752;        // 768
    float* v_m     = sc_ + 499520;        // 768
    float* c_m     = sc_ + 500288;        // 1 (+pad)
    float* at_part = sc_ + 500352;        // 98304 (ends 598656)
    float* ni      = sc_ + 598656;        // 24576
    float* nt      = sc_ + 623232;        // 24576
    bf16* text_bf  = (bf16*)(sc_ + 672384);    // 12.58M bf16
    bf16* img_bf   = (bf16*)(sc_ + 6963840);   // 1204224 bf16
    bf16* wt_t     = (bf16*)(sc_ + 7565952);   // 589824 bf16 (absorbs img OOB reads)
    bf16* wt_i     = (bf16*)(sc_ + 7860864);   // 589824 bf16 (ends 8155776 < 12.58M)

    // ---- ws holds only what out_kernel reads ----
    float* ws    = (float*)d_ws;
    float* s_txt = ws;                    // 16384
    float* s_mm  = ws + 16384;            // 32 (+pad)
    float* T     = ws + 16448;            // 24576

    // 0. fused prep: rank-1 collapses + img->bf16 + weight transposes
    prep_misc<<<dim3(385 + 588 + 288), dim3(256), 0, stream>>>(
        ft_w, fm_w, fm_b, fg_w, v_f, v_m, c_m, img, img_bf, t2_w, i1_w, wt_t, wt_i);
    // 0b. text fp32 -> bf16 + s_txt (needs v_f)
    prep_text<<<dim3(MT / 4), dim3(256), 0, stream>>>(text, v_f, text_bf, s_txt);
    // 1/2. merged score GEMMs (256^2 tile, 4-phase schedule + setprio)
    gemm4<<<dim3(NWG3), dim3(512), 0, stream>>>(
        text_bf, wt_t, a2_w + HD, k_part, img_bf, wt_i, a1_w + HD, i_part);
    // 3. fused reduce + softmax + weighted sums (vectorized) -> at_part, aimg
    wsum3<<<dim3(224), dim3(256), 0, stream>>>(
        k_part, i_part, text_bf, img, at_part, aimg);
    // 4. GMF GEMVs (f32x4 weight loads; ni_nt folds at_part reduce)
    ni_nt3<<<dim3(BD, 6, 2), dim3(256), 0, stream>>>(
        aimg, at_part, gi_w, gi_b, gt_w, gt_b, ni, nt);
    gateT3<<<dim3(BD, 6), dim3(256), 0, stream>>>(
        ni, nt, gg_w, gg_b, v_m, c_m, fg_b, fr_w, fr_b, T, s_mm);
    // 5. output (reads ws only; overwrites all of d_out)
    out_kernel<<<dim3((MT * HD / 4) / 256), dim3(256), 0, stream>>>(s_txt, s_mm, T, out);
}